// Round 1
// 712.912 us; speedup vs baseline: 1.8648x; 1.8648x over previous
//
#include <hip/hip_runtime.h>

// QRNN: y = inp @ W^T + b -> z=tanh(y0), f=sig(y1), o=sig(y2)
//       h_t = f*z + (1-f)*h;  out0 = sig(o)*h [B,S,H];  out1 = h_{S-1} [B,H]
// Established (NaN-chain r1/r2 vs r3): inputs fp32, output fp32.
// r5: epilogue stores ACTIVATED gates; K3 uses o directly (no double sigmoid).
// r6 (this round): GEMM was stall-bound at 206 TF (MfmaUtil 8.5%, HBM 13%) --
//   fp32->bf16 register staging (16 float4 loads + 64 f2bf + 16 ds_write per
//   thread per K-tile) starved the MFMA pipe. Replace with the m97 ladder
//   structure: pre-convert inp/W to bf16 (K0, ~40us memory-bound), then
//   global_load_lds width=16 direct staging. XOR-swizzled LDS reads kept by
//   pre-swizzling the per-lane GLOBAL source (linear LDS dest, rule #21):
//   LDS[row][slot] holds k-group slot^(row&7); read side unchanged+verified.
// K1: bf16 MFMA GEMM 128x128, BK=64, 4 waves 2x2, 16x16x32_bf16,
//     fused bias+activation epilogue -> gates in ws.
// K2: per-chunk linear-recurrence aggregates (G, A)  [h' = g*h + a]
// K3: prefix-fold aggregates + replay chunk + output gate (fp32 stores)

typedef unsigned short ushort_t;
typedef __bf16 bf16x8 __attribute__((ext_vector_type(8)));
typedef float f32x4 __attribute__((ext_vector_type(4)));
typedef ushort_t us8 __attribute__((ext_vector_type(8)));

__device__ __forceinline__ ushort_t f2bf(float f) {
  unsigned int x = __builtin_bit_cast(unsigned int, f);
  x += 0x7fffu + ((x >> 16) & 1u);  // RNE
  return (ushort_t)(x >> 16);
}
__device__ __forceinline__ float bf2f(ushort_t u) {
  unsigned int x = ((unsigned int)u) << 16;
  return __builtin_bit_cast(float, x);
}
__device__ __forceinline__ float loadg(const float* p) { return *p; }
__device__ __forceinline__ float loadg(const ushort_t* p) { return bf2f(*p); }
__device__ __forceinline__ void storeg(float* p, float v) { *p = v; }
__device__ __forceinline__ void storeg(ushort_t* p, float v) { *p = f2bf(v); }

__device__ __forceinline__ float sig_f(float x) { return 1.0f / (1.0f + __expf(-x)); }
__device__ __forceinline__ float tanh_f(float x) { return 1.0f - 2.0f / (1.0f + __expf(2.0f * x)); }

// async global->LDS, 16B per lane; LDS dest is WAVE-UNIFORM base + lane*16.
__device__ __forceinline__ void gload_lds16(const ushort_t* g, ushort_t* l) {
  __builtin_amdgcn_global_load_lds(
      (const __attribute__((address_space(1))) void*)g,
      (__attribute__((address_space(3))) void*)l, 16, 0, 0);
}

// ---------------- K0: fp32 -> bf16 pre-convert (RNE, same as old in-GEMM) ----
__global__ void __launch_bounds__(256) cvt_f32_bf16(
    const float* __restrict__ in, ushort_t* __restrict__ out, long n8) {
  long i = (long)blockIdx.x * 256 + threadIdx.x;
  const long stride = (long)gridDim.x * 256;
  for (; i < n8; i += stride) {
    const float4 a = ((const float4*)in)[2 * i];
    const float4 c = ((const float4*)in)[2 * i + 1];
    us8 w;
    w[0] = f2bf(a.x); w[1] = f2bf(a.y); w[2] = f2bf(a.z); w[3] = f2bf(a.w);
    w[4] = f2bf(c.x); w[5] = f2bf(c.y); w[6] = f2bf(c.z); w[7] = f2bf(c.w);
    ((us8*)out)[i] = w;
  }
}

// ---------------- K1: GEMM + activation epilogue ----------------
// A [M,K] bf16, Wt [N,K] bf16 (B^T layout), out [M,N] ACTIVATED gates.
// 128x128 tile, BK=64, 4 waves 2x2, each wave 4x4 MFMA 16x16x32 tiles.
// LDS: linear [row][64] bf16 dest for global_load_lds; swizzle realized by
// fetching global k-group (slot ^ (row&7)) into slot -> read path identical
// to the previously verified register-staged kernel.
template <typename GT>
__global__ void __launch_bounds__(256) gemm_gates(
    const ushort_t* __restrict__ A, const ushort_t* __restrict__ Wt,
    const float* __restrict__ bias, GT* __restrict__ out,
    int M, int N, int K) {
  constexpr int BK = 64;
  __shared__ __align__(16) ushort_t As[128 * BK];
  __shared__ __align__(16) ushort_t Bs[128 * BK];
  const int tid = threadIdx.x;
  const int lane = tid & 63;
  const int wv = tid >> 6;  // 0..3
  const int nblk = N >> 7;
  const int bn = blockIdx.x % nblk;
  const int bm = blockIdx.x / nblk;
  const int m0 = bm << 7, n0 = bn << 7;
  const int wm = (wv >> 1) << 6, wn = (wv & 1) << 6;

  f32x4 acc[4][4] = {};

  // Staging geometry: per wave-issue, 64 lanes cover 8 rows x 8 slots of 16B.
  // lane l -> LDS row base+ (l>>3), slot (l&7). Global k-group pre-swizzled.
  const int srow = lane >> 3;                 // row within 8-row group
  const int sg = (lane & 7) ^ srow;           // global 16B k-group to fetch

  for (int kt = 0; kt < K; kt += BK) {
    __syncthreads();
#pragma unroll
    for (int i = 0; i < 4; ++i) {
      const int rbase = wv * 32 + i * 8;  // wave-uniform
      gload_lds16(&A[(size_t)(m0 + rbase + srow) * K + kt + sg * 8],
                  &As[rbase * 64]);
      gload_lds16(&Wt[(size_t)(n0 + rbase + srow) * K + kt + sg * 8],
                  &Bs[rbase * 64]);
    }
    __syncthreads();  // compiler emits vmcnt(0) drain here (m97 structure)
#pragma unroll
    for (int ks = 0; ks < 2; ++ks) {
      bf16x8 af[4], bfr[4];
#pragma unroll
      for (int t = 0; t < 4; ++t) {
        const int ar = wm + t * 16 + (lane & 15);
        const int ag = ((ks << 2) + (lane >> 4)) ^ (ar & 7);
        af[t] = *(const bf16x8*)&As[ar * 64 + ag * 8];
        const int br = wn + t * 16 + (lane & 15);
        const int bg = ((ks << 2) + (lane >> 4)) ^ (br & 7);
        bfr[t] = *(const bf16x8*)&Bs[br * 64 + bg * 8];
      }
#pragma unroll
      for (int i = 0; i < 4; ++i)
#pragma unroll
        for (int j = 0; j < 4; ++j)
          acc[i][j] =
              __builtin_amdgcn_mfma_f32_16x16x32_bf16(af[i], bfr[j], acc[i][j], 0, 0, 0);
    }
  }

  // Epilogue. C/D layout (m89/m91): col = lane&15, row = (lane>>4)*4 + reg.
  const int gcat = n0 >> 10;  // 0:z(tanh) 1:f(sig) 2:o(sig); uniform per block
  const int cn = lane & 15;
  const int cm = (lane >> 4) << 2;
#pragma unroll
  for (int j = 0; j < 4; ++j) {
    const int n = n0 + wn + j * 16 + cn;
    const float bv = bias[n];
#pragma unroll
    for (int i = 0; i < 4; ++i) {
#pragma unroll
      for (int r = 0; r < 4; ++r) {
        const int m = m0 + wm + i * 16 + cm + r;
        const float y = acc[i][j][r] + bv;
        const float v = (gcat == 0) ? tanh_f(y) : sig_f(y);
        storeg(&out[(size_t)m * N + n], v);
      }
    }
  }
}

// ---------------- K2: chunk aggregates ----------------
// h_t = f*z + (1-f)*h == g*h + a, g=1-f, a=f*z. Chunk: h_end = Aa + G*h_in.
// gates hold ACTIVATED z,f.
template <typename GT>
__global__ void __launch_bounds__(256) qrnn_chunk_agg(
    const GT* __restrict__ gates, float* __restrict__ aggG,
    float* __restrict__ aggA, int b0, int S, int H, int C, int L) {
  const int nhb = H >> 8;
  const int hb = blockIdx.x % nhb;
  const int c = (blockIdx.x / nhb) % C;
  const int bl = blockIdx.x / (nhb * C);  // local batch within group
  const int h = (hb << 8) + threadIdx.x;
  const int N3 = 3 * H;
  const GT* pz = gates + ((size_t)(bl * S + c * L)) * N3 + h;
  const GT* pf = pz + H;
  float G = 1.0f, Aa = 0.0f;
#pragma unroll 4
  for (int j = 0; j < L; ++j) {
    const float z = loadg(pz);
    const float f = loadg(pf);
    const float g = 1.0f - f;
    Aa = fmaf(g, Aa, f * z);
    G *= g;
    pz += N3;
    pf += N3;
  }
  const size_t idx = ((size_t)((b0 + bl) * C + c)) * H + h;
  aggG[idx] = G;
  aggA[idx] = Aa;
}

// ---------------- K3: prefix fold + replay + output gate ----------------
// gates hold ACTIVATED z,f,o -> o is used DIRECTLY (no second sigmoid!).
template <typename GT>
__global__ void __launch_bounds__(256) qrnn_scan_apply(
    const GT* __restrict__ gates, const float* __restrict__ aggG,
    const float* __restrict__ aggA, float* __restrict__ out,
    int b0, int B, int S, int H, int C, int L) {
  const int nhb = H >> 8;
  const int hb = blockIdx.x % nhb;
  const int c = (blockIdx.x / nhb) % C;
  const int bl = blockIdx.x / (nhb * C);
  const int bg = b0 + bl;  // global batch
  const int h = (hb << 8) + threadIdx.x;
  const int N3 = 3 * H;

  float hc = 0.0f;  // h at chunk start (c block-uniform -> no divergence)
  for (int cc = 0; cc < c; ++cc) {
    const size_t idx = ((size_t)(bg * C + cc)) * H + h;
    hc = fmaf(aggG[idx], hc, aggA[idx]);
  }

  const GT* pz = gates + ((size_t)(bl * S + c * L)) * N3 + h;
  const GT* pf = pz + H;
  const GT* po = pf + H;
  size_t oidx = ((size_t)(bg * S + c * L)) * H + h;
#pragma unroll 4
  for (int j = 0; j < L; ++j) {
    const float z = loadg(pz);
    const float f = loadg(pf);
    const float o = loadg(po);  // already sigmoid(y_o)
    hc = fmaf(1.0f - f, hc, f * z);
    out[oidx] = o * hc;
    pz += N3; pf += N3; po += N3; oidx += H;
  }
  if (c == C - 1) {  // final state c[:, -1] -> second output [B,H]
    out[(size_t)B * S * H + (size_t)bg * H + h] = hc;
  }
}

template <typename GT>
static void run_groups(const float* inp, const ushort_t* Wbf, const float* b,
                       float* out, ushort_t* Abf, void* gates_ws, float* aggG,
                       float* aggA, int Bg, int B, int S, int H, int K, int C,
                       int L, hipStream_t stream) {
  const int N = 3 * H;
  GT* gates = (GT*)gates_ws;
  for (int b0 = 0; b0 < B; b0 += Bg) {
    const int Mg = Bg * S;
    // K0: convert this group's inp slab to bf16
    const long n8 = (long)Mg * K / 8;
    const long cg = (n8 + 255) / 256;
    const int cgrid = (int)(cg < 2048 ? cg : 2048);
    cvt_f32_bf16<<<cgrid, 256, 0, stream>>>(inp + (size_t)b0 * S * K, Abf, n8);
    const int gemm_grid = (Mg / 128) * (N / 128);
    const int scan_grid = Bg * C * (H / 256);
    gemm_gates<GT><<<gemm_grid, 256, 0, stream>>>(Abf, Wbf, b, gates, Mg, N, K);
    qrnn_chunk_agg<GT><<<scan_grid, 256, 0, stream>>>(
        gates, aggG, aggA, b0, S, H, C, L);
    qrnn_scan_apply<GT><<<scan_grid, 256, 0, stream>>>(
        gates, aggG, aggA, out, b0, B, S, H, C, L);
  }
}

extern "C" void kernel_launch(void* const* d_in, const int* in_sizes, int n_in,
                              void* d_out, int out_size, void* d_ws, size_t ws_size,
                              hipStream_t stream) {
  (void)in_sizes; (void)n_in; (void)out_size;
  const float* inp = (const float*)d_in[0];  // [B,S,D] fp32
  const float* W = (const float*)d_in[1];    // [3H,D] fp32
  const float* b = (const float*)d_in[2];    // [3H] fp32
  float* out = (float*)d_out;                // [B,S,H] ++ [B,H] fp32

  constexpr int B = 16, S = 2048, H = 1024, K = 1024;
  constexpr int C = 16, L = S / C;
  const int N3 = 3 * H;

  // ws layout: [aggG fp32 B*C*H][aggA fp32 B*C*H][Wbf bf16 3H*K]
  //            [Abf bf16 Bg*S*K][gates (group-local)]
  const size_t agg_elems = (size_t)B * C * H;
  float* aggG = (float*)d_ws;
  float* aggA = aggG + agg_elems;
  ushort_t* Wbf = (ushort_t*)(aggA + agg_elems);
  ushort_t* Abf = Wbf + (size_t)N3 * K;
  const size_t hdr =
      2 * agg_elems * sizeof(float) + (size_t)N3 * K * sizeof(ushort_t);

  // Largest batch-group whose (Abf + gates) fit; prefer fp32 gates (exact scan).
  int Bg = 0;
  bool f32g = true;
  for (int g = 16; g >= 1; g >>= 1) {
    const size_t need =
        hdr + (size_t)g * S * K * sizeof(ushort_t) + (size_t)g * S * N3 * sizeof(float);
    if (need <= ws_size) { Bg = g; break; }
  }
  if (!Bg) {
    f32g = false;
    for (int g = 16; g >= 1; g >>= 1) {
      const size_t need = hdr + (size_t)g * S * K * sizeof(ushort_t) +
                          (size_t)g * S * N3 * sizeof(ushort_t);
      if (need <= ws_size) { Bg = g; break; }
    }
  }
  if (!Bg) return;
  void* gates_ws = (void*)(Abf + (size_t)Bg * S * K);

  // Convert W once (RNE, identical numerics to the old in-GEMM convert).
  {
    const long n8w = (long)N3 * K / 8;
    const long cg = (n8w + 255) / 256;
    const int grid = (int)(cg < 2048 ? cg : 2048);
    cvt_f32_bf16<<<grid, 256, 0, stream>>>(W, Wbf, n8w);
  }

  if (f32g) {
    run_groups<float>(inp, Wbf, b, out, Abf, gates_ws, aggG, aggA, Bg,
                      B, S, H, K, C, L, stream);
  } else {
    run_groups<ushort_t>(inp, Wbf, b, out, Abf, gates_ws, aggG, aggA, Bg,
                         B, S, H, K, C, L, stream);
  }
}